// Round 16
// baseline (1616.732 us; speedup 1.0000x reference)
//
#include <hip/hip_runtime.h>
#include <stdint.h>

// ---------------- problem constants ----------------
#define PB 16            // batches
#define PN 8192          // points per batch
#define PG 512           // FPS samples (centers) per batch
#define PK 32            // knn group size
#define PTOK 384
#define PM (PB*PG)       // 8192 groups total
#define PMK (PM*PK)      // 262144 MLP rows
#define NWORK 240        // knn worker blocks (16 fps + 240 = 256 = #CUs, co-resident)
#define NTASK (PM/4)     // 2048 quad tasks (4 consecutive centers of one batch)
static constexpr float BN_EPS_C = 1e-5f;

typedef short bh8  __attribute__((ext_vector_type(8)));
typedef float f32x4 __attribute__((ext_vector_type(4)));

__device__ __forceinline__ short f2bf(float f){
  unsigned u = __float_as_uint(f);
  unsigned r = u + 0x7fffu + ((u>>16)&1u);   // RNE
  return (short)(r>>16);
}
__device__ __forceinline__ float bf2f(short s){
  return __uint_as_float(((unsigned)(unsigned short)s)<<16);
}

// ---------------- 1. mega2: 16 FPS producers + 240 KNN workers (R15, unchanged) ----
__global__ __launch_bounds__(1024, 4) void mega2_kernel(
    const float* __restrict__ points, float* __restrict__ centers,
    int* __restrict__ prog, int* __restrict__ qhead,
    float* __restrict__ grp){
#pragma clang fp contract(off)
  __shared__ __align__(16) char SMEM[150528];
  const int t = threadIdx.x;
  const int lane = t & 63;

  if (blockIdx.x < PB){
    // ================= FPS role (proven 504us shape) =================
    const int b = blockIdx.x;
    const float* P = points + (size_t)b*PN*3;
    float4* Lc = (float4*)SMEM;                          // 128 KB
    unsigned short* sidx = (unsigned short*)(SMEM + 131072);  // 16 KB
    int* shist = (int*)(SMEM + 147456);                  // 2 KB
    int* spart = (int*)(SMEM + 149504);                  // 256 B
    unsigned long long* swa = (unsigned long long*)(SMEM + 149760);
    if (t < 512) shist[t] = 0;
    if (t < 3)   swa[t] = 0ull;
    __syncthreads();
    int mycell[8];
#pragma unroll
    for (int i=0;i<8;i++){
      int j = i*1024 + t;
      float x=P[j*3+0], y=P[j*3+1], z=P[j*3+2];
      Lc[j] = make_float4(x,y,z,0.f);
      int qx=(int)fminf(fmaxf((x+4.f)*1.0f,0.f),7.f);
      int qy=(int)fminf(fmaxf((y+4.f)*1.0f,0.f),7.f);
      int qz=(int)fminf(fmaxf((z+4.f)*1.0f,0.f),7.f);
      int mc = (qx&1)|((qx&2)<<2)|((qx&4)<<4)
             | ((qy&1)<<1)|((qy&2)<<3)|((qy&4)<<5)
             | ((qz&1)<<2)|((qz&2)<<4)|((qz&4)<<6);
      mycell[i]=mc;
      atomicAdd(&shist[mc],1);
    }
    __syncthreads();
    if (t < 64){
      int acc=0;
#pragma unroll
      for (int k=0;k<8;k++){ int h=shist[t*8+k]; shist[t*8+k]=acc; acc+=h; }
      spart[t]=acc;
    }
    __syncthreads();
    if (t==0){ int acc=0; for (int k=0;k<64;k++){ int h=spart[k]; spart[k]=acc; acc+=h; } }
    __syncthreads();
    if (t < 64){
      int off=spart[t];
#pragma unroll
      for (int k=0;k<8;k++) shist[t*8+k] += off;
    }
    __syncthreads();
#pragma unroll
    for (int i=0;i<8;i++){
      int j = i*1024 + t;
      int r = atomicAdd(&shist[mycell[i]],1);
      sidx[r] = (unsigned short)j;
    }
    __syncthreads();
    float px[8],py[8],pz[8],md[8]; int lowc[8];
    float tlx=1e30f,tly=1e30f,tlz=1e30f,thx=-1e30f,thy=-1e30f,thz=-1e30f;
#pragma unroll
    for (int i=0;i<8;i++){
      int oj = sidx[t*8+i];
      float4 p4 = Lc[oj];
      float x=p4.x, y=p4.y, z=p4.z;
      px[i]=x; py[i]=y; pz[i]=z; md[i]=1e10f; lowc[i]=PN-1-oj;
      tlx=fminf(tlx,x); thx=fmaxf(thx,x);
      tly=fminf(tly,y); thy=fmaxf(thy,y);
      tlz=fminf(tlz,z); thz=fmaxf(thz,z);
    }
#pragma unroll
    for (int off=32; off; off>>=1){
      tlx=fminf(tlx,__shfl_xor(tlx,off)); thx=fmaxf(thx,__shfl_xor(thx,off));
      tly=fminf(tly,__shfl_xor(tly,off)); thy=fmaxf(thy,__shfl_xor(thy,off));
      tlz=fminf(tlz,__shfl_xor(tlz,off)); thz=fmaxf(thz,__shfl_xor(thz,off));
    }
    unsigned long long wkey = ((unsigned long long)0x7F800000u)<<32;
    float cx=P[0], cy=P[1], cz=P[2];
    if (t==0){ float* c = centers + (size_t)b*PG*3; c[0]=cx; c[1]=cy; c[2]=cz; }
    __syncthreads();
    for (int g=1; g<PG; g++){
      const int sl = g%3, ns = (g+1)%3;
      float ddx=fmaxf(fmaxf(tlx-cx, cx-thx),0.f);
      float ddy=fmaxf(fmaxf(tly-cy, cy-thy),0.f);
      float ddz=fmaxf(fmaxf(tlz-cz, cz-thz),0.f);
      float dmin2=((ddx*ddx+ddy*ddy)+ddz*ddz)*0.999999f;
      if (!(dmin2 >= __uint_as_float((unsigned)(wkey>>32)))){
        unsigned long long bk = 0ull;
#pragma unroll
        for (int i=0;i<8;i++){
          float dx=px[i]-cx, dy=py[i]-cy, dz=pz[i]-cz;
          float d2 = (dx*dx + dy*dy) + dz*dz;
          md[i] = fminf(md[i], d2);
          unsigned long long ki = ((unsigned long long)__float_as_uint(md[i])<<32)
                                | (unsigned)lowc[i];
          if (ki > bk) bk = ki;
        }
#pragma unroll
        for (int mask=32; mask; mask>>=1){
          unsigned long long o = __shfl_xor(bk, mask);
          if (o > bk) bk = o;
        }
        wkey = bk;
      }
      if (lane==0) atomicMax(&swa[sl], wkey);
      if (t==0) swa[ns] = 0ull;
      __syncthreads();
      unsigned long long w = swa[sl];
      int j = PN-1 - (int)(w & 0xFFFFFFFFu);
      float4 c4 = Lc[j];
      cx = c4.x; cy = c4.y; cz = c4.z;
      if (t==0){
        float* cc = centers + ((size_t)b*PG + g)*3;
        cc[0]=cx; cc[1]=cy; cc[2]=cz;
        if ((g & 3) == 3)    // publish quad: centers 0..g now agent-visible
          __hip_atomic_store(prog + b, g + 1, __ATOMIC_RELEASE, __HIP_MEMORY_SCOPE_AGENT);
      }
    }
    // fall through: help drain remaining knn tasks
  }

  // ================= KNN worker role (u32 keys, static knockout) =================
  unsigned long long* ks_k = (unsigned long long*)(SMEM + 149504); // [4][2][4]
  int*   ks_idx = (int*)(SMEM + 149760);           // [4][32]
  float* ks_c   = (float*)(SMEM + 150272);         // [4][3]
  int*   s_task = (int*)(SMEM + 150320);

  for(;;){
    if (t == 0){
      int id = atomicAdd(qhead, 1);
      s_task[0] = id;
      if (id < NTASK){
        int bb = id & (PB-1), qq = id >> 4;
        int need = qq*4 + 4;
        while (__hip_atomic_load(prog + bb, __ATOMIC_ACQUIRE, __HIP_MEMORY_SCOPE_AGENT) < need)
          __builtin_amdgcn_s_sleep(10);
      }
    }
    __syncthreads();
    const int id = s_task[0];
    if (id >= NTASK) break;                        // uniform
    const int b = id & (PB-1), q = id >> 4;
    const int m0 = b*PG + q*4;                     // first center of quad
    const float* P = points + (size_t)b*PN*3;
    const int sub = t >> 8, tt = t & 255;          // 4 subgroups x 256 threads

    if (tt == 0){
      const float* cp = centers + (size_t)(m0 + sub)*3;
      ks_c[sub*3+0] = __hip_atomic_load(cp+0, __ATOMIC_ACQUIRE, __HIP_MEMORY_SCOPE_AGENT);
      ks_c[sub*3+1] = __hip_atomic_load(cp+1, __ATOMIC_ACQUIRE, __HIP_MEMORY_SCOPE_AGENT);
      ks_c[sub*3+2] = __hip_atomic_load(cp+2, __ATOMIC_ACQUIRE, __HIP_MEMORY_SCOPE_AGENT);
    }
    __syncthreads();
    {
      const float cx=ks_c[sub*3+0], cy=ks_c[sub*3+1], cz=ks_c[sub*3+2];
      const float cn = (cx*cx + cy*cy) + cz*cz;
      unsigned key[PK];                            // 32 VGPRs; index implicit in slot
#pragma unroll
      for (int i=0;i<PK;i++){
        int j = i*256 + tt;
        float x=P[j*3+0], y=P[j*3+1], z=P[j*3+2];
        float pn = (x*x + y*y) + z*z;
        float e  = (cx*x + cy*y) + cz*z;
        float d2 = (cn + pn) - 2.0f*e;             // reference formula
        unsigned u = __float_as_uint(d2);
        u ^= (u & 0x80000000u) ? 0xFFFFFFFFu : 0x80000000u;   // total order
        key[i] = u;
      }
      unsigned lmin = key[0]; int li = 0;          // strict <: smallest slot wins
#pragma unroll
      for (int i=1;i<PK;i++) if (key[i] < lmin){ lmin = key[i]; li = i; }
      unsigned long long lkey = ((unsigned long long)lmin << 32)
                              | (unsigned)(li*256 + tt);
      const int widx = tt >> 6;
      for (int it=0; it<PK; it++){
        unsigned long long v = lkey;
#pragma unroll
        for (int off=32; off; off>>=1){
          unsigned long long o = __shfl_down(v, off);
          if (o < v) v = o;
        }
        if (lane==0) ks_k[sub*8 + (it&1)*4 + widx] = v;
        __syncthreads();                           // block-wide, uniform rounds
        unsigned long long w = ks_k[sub*8 + (it&1)*4 + 0];
#pragma unroll
        for (int qq=1;qq<4;qq++){
          unsigned long long o = ks_k[sub*8 + (it&1)*4 + qq];
          if (o < w) w = o;
        }
        int wj = (int)(w & 0xFFFFFFFFull);
        if (tt==0) ks_idx[sub*32 + it] = wj;
        if ((wj & 255) == tt){                     // owner: kill slot (STATIC idx), rescan
          int slot = wj >> 8;
#pragma unroll
          for (int i=0;i<PK;i++) if (i == slot) key[i] = 0xFFFFFFFFu;
          lmin = key[0]; li = 0;
#pragma unroll
          for (int i=1;i<PK;i++) if (key[i] < lmin){ lmin = key[i]; li = i; }
          lkey = ((unsigned long long)lmin << 32) | (unsigned)(li*256 + tt);
        }
      }
      __syncthreads();
      if (tt < PK*3){
        int k = tt/3, c = tt - k*3;
        int j = ks_idx[sub*32 + k];
        grp[((size_t)(m0 + sub)*PK + k)*3 + c] = P[j*3+c] - ks_c[sub*3+c];
      }
    }
    // claim-barrier at loop top separates ks_c/ks_idx reuse across tasks
  }
}

// ---------------- 2. fused MLP v3: 128-row, weights direct from L2 ---------------
// R16 change: B-operands (weights, read-only, ~1MB, L2-resident) are loaded
// straight global->VGPR per fragment instead of staged through LDS. This deletes
// s_bst and ~80 of ~90 per-block barriers (each was a block-wide vmcnt(0) drain
// at 1 block/CU). A-operands keep LDS + phase-transition barriers (11 total).
// Operand bytes and MFMA accumulate order are unchanged -> bit-identical output.
__global__ __launch_bounds__(512, 2) void mlp_kernel(const float* __restrict__ grp,
                                                     const float* __restrict__ w1,
                                                     const float* __restrict__ sc1,
                                                     const float* __restrict__ sh1,
                                                     const short* __restrict__ w2b,
                                                     const float* __restrict__ b2,
                                                     const short* __restrict__ w3ab,
                                                     const short* __restrict__ w3bb,
                                                     const float* __restrict__ sc2,
                                                     const float* __restrict__ sh2,
                                                     const short* __restrict__ w4b,
                                                     const float* __restrict__ b4,
                                                     float* __restrict__ tokens){
  __shared__ __align__(16) short s_f1f3[16384];    // 32 KB: f1 [4][128][32] then f3-chunk
  __shared__ __align__(16) short s_f2[32768];      // 64 KB: f2 [8][128][32]
  __shared__ __align__(16) short s_g[1024];        //  2 KB: g  [4][256]
  const int t = threadIdx.x;
  const int lane = t & 63, wid = t >> 6;
  const int mh = wid >> 1, nq = wid & 1;           // 4 M-waves x 2 N-waves
  const int B0 = blockIdx.x * 128;                 // first row of block
  const int G0 = blockIdx.x * 4;                   // first group of block
  const int frow = lane & 15;                      // fragment row
  const int fk   = (lane >> 4) * 8;                // fragment k offset
  const int rb   = (lane >> 4) * 4;                // C/D row base
  const int cb   = lane & 15;                      // C/D col

  // ---- phase A: layer1 into f1 (LDS) ----
  {
    int r = t & 127, dg = t >> 7;                  // thread: row r, d-range dg*32..+31
    float x0 = grp[(size_t)(B0+r)*3 + 0];
    float x1 = grp[(size_t)(B0+r)*3 + 1];
    float x2 = grp[(size_t)(B0+r)*3 + 2];
#pragma unroll
    for (int dd=0; dd<32; dd++){
      int d = dg*32 + dd;
      float a = x0*w1[d*3+0] + x1*w1[d*3+1] + x2*w1[d*3+2];
      float y = a*sc1[d] + sh1[d];
      s_f1f3[dg*4096 + r*32 + dd] = f2bf(fmaxf(y, 0.f));
    }
  }
  __syncthreads();                                 // [1] f1 ready

  // ---- phase B: f2 = f1 @ w2^T + b2 (K=128, N=256; weights direct) ----
  {
    f32x4 accB[2][8] = {};
#pragma unroll
    for (int kc=0; kc<4; kc++){                    // K chunks of 32 (order = old)
      bh8 af[2], bf[8];
#pragma unroll
      for (int i=0;i<2;i++)
        af[i] = *(const bh8*)&s_f1f3[kc*4096 + (mh*32 + i*16 + frow)*32 + fk];
#pragma unroll
      for (int j=0;j<8;j++)
        bf[j] = *(const bh8*)&w2b[(size_t)(nq*128 + j*16 + frow)*128 + kc*32 + fk];
#pragma unroll
      for (int i=0;i<2;i++)
#pragma unroll
        for (int j=0;j<8;j++)
          accB[i][j] = __builtin_amdgcn_mfma_f32_16x16x32_bf16(af[i], bf[j], accB[i][j], 0,0,0);
    }
    // epilogue: +b2, bf16, write f2 chunks
#pragma unroll
    for (int i=0;i<2;i++)
#pragma unroll
      for (int j=0;j<8;j++){
        int col = nq*128 + j*16 + cb;
#pragma unroll
        for (int r=0;r<4;r++){
          int row = mh*32 + i*16 + rb + r;
          s_f2[(col>>5)*4096 + row*32 + (col&31)] = f2bf(accB[i][j][r] + b2[col]);
        }
      }
  }
  __syncthreads();                                 // [2] f2 ready

  // ---- phase C: g = maxpool_k(f2) per group ----
  {
#pragma unroll
    for (int task=0; task<2; task++){
      int g = (t>>8) + task*2;                     // 0..3
      int col = t & 255;
      int kc = col >> 5, c5 = col & 31;
      float mx = -3.4e38f;
#pragma unroll
      for (int kk=0; kk<PK; kk++)
        mx = fmaxf(mx, bf2f(s_f2[kc*4096 + (g*32 + kk)*32 + c5]));
      s_g[g*256 + col] = f2bf(mx);
    }
  }
  __syncthreads();                                 // [3] g ready

  // ---- phases D+E: f3 chunks (concat GEMM) + f4 partial accumulation ----
  f32x4 acc4[2][12] = {};                          // persistent: 128 x 384 over 8 waves
  for (int nc=0; nc<4; nc++){
    // --- D: f3c[128][128] = relu(bn2([g,f2] @ w3[nc*128..][:]^T)); weights direct ---
    f32x4 acc3[2][4] = {};
#pragma unroll 4
    for (int kk=0; kk<16; kk++){                   // concat-K chunks of 32 (order = old)
      int k = kk*32;
      const short* w3s = (k < 256) ? w3ab : w3bb;
      int kb = (k < 256) ? k : (k - 256);
      bh8 af[2], bf[4];
      if (k < 256){
        bh8 gv = *(const bh8*)&s_g[mh*256 + k + fk];
        af[0] = gv; af[1] = gv;                    // broadcast: wave tile = 1 group
      } else {
        int kc = (k - 256) >> 5;
#pragma unroll
        for (int i=0;i<2;i++)
          af[i] = *(const bh8*)&s_f2[kc*4096 + (mh*32 + i*16 + frow)*32 + fk];
      }
#pragma unroll
      for (int j=0;j<4;j++)
        bf[j] = *(const bh8*)&w3s[(size_t)(nc*128 + nq*64 + j*16 + frow)*256 + kb + fk];
#pragma unroll
      for (int i=0;i<2;i++)
#pragma unroll
        for (int j=0;j<4;j++)
          acc3[i][j] = __builtin_amdgcn_mfma_f32_16x16x32_bf16(af[i], bf[j], acc3[i][j], 0,0,0);
    }
    __syncthreads();                               // [4a] prev-E reads of f1f3 done
    // D epilogue: bn2 + relu + bf16 -> f3 chunk (reuses f1 region)
#pragma unroll
    for (int i=0;i<2;i++)
#pragma unroll
      for (int j=0;j<4;j++){
        int cl = nq*64 + j*16 + cb;                // local f-col 0..127
        int f  = nc*128 + cl;
        float s = sc2[f], h = sh2[f];
#pragma unroll
        for (int r=0;r<4;r++){
          int row = mh*32 + i*16 + rb + r;
          float v = acc3[i][j][r]*s + h;
          s_f1f3[(cl>>5)*4096 + row*32 + (cl&31)] = f2bf(fmaxf(v, 0.f));
        }
      }
    __syncthreads();                               // [4b] f3 chunk ready
    // --- E: acc4 += f3c @ w4[:, nc*128..]^T (weights direct; j split 2x6) ---
#pragma unroll
    for (int kk=0; kk<4; kk++){                    // K chunks of 32 (order = old)
      int kcol = nc*128 + kk*32;
      bh8 af[2];
#pragma unroll
      for (int i=0;i<2;i++)
        af[i] = *(const bh8*)&s_f1f3[kk*4096 + (mh*32 + i*16 + frow)*32 + fk];
#pragma unroll
      for (int half=0; half<2; half++){
        bh8 bf[6];
#pragma unroll
        for (int j=0;j<6;j++){
          int jj = half*6 + j;
          bf[j] = *(const bh8*)&w4b[(size_t)(nq*192 + jj*16 + frow)*512 + kcol + fk];
        }
#pragma unroll
        for (int i=0;i<2;i++)
#pragma unroll
          for (int j=0;j<6;j++)
            acc4[i][half*6+j] = __builtin_amdgcn_mfma_f32_16x16x32_bf16(af[i], bf[j], acc4[i][half*6+j], 0,0,0);
      }
    }
  }

  // ---- phase F: tokens = maxpool_k(f4) + b4 (wave mh owns group mh) ----
#pragma unroll
  for (int j=0;j<12;j++){
    int col = nq*192 + j*16 + cb;
    float mx = -3.4e38f;
#pragma unroll
    for (int i=0;i<2;i++)
#pragma unroll
      for (int r=0;r<4;r++)
        mx = fmaxf(mx, acc4[i][j][r]);
    mx = fmaxf(mx, __shfl_xor(mx, 16));
    mx = fmaxf(mx, __shfl_xor(mx, 32));
    if (lane < 16)
      tokens[(size_t)(G0 + mh)*PTOK + col] = mx + b4[col];
  }
}

// ---------------- 0. weight conversion + BN folding + sync reset ----------------
__global__ __launch_bounds__(256) void prep_kernel(const float* __restrict__ w2,
    const float* __restrict__ w3, const float* __restrict__ w4,
    const float* __restrict__ g1, const float* __restrict__ be1,
    const float* __restrict__ mu1, const float* __restrict__ va1,
    const float* __restrict__ g2, const float* __restrict__ be2,
    const float* __restrict__ mu2, const float* __restrict__ va2,
    short* __restrict__ w2b, short* __restrict__ w3ab, short* __restrict__ w3bb,
    short* __restrict__ w4b, float* __restrict__ sc1, float* __restrict__ sh1,
    float* __restrict__ sc2, float* __restrict__ sh2,
    int* __restrict__ prog, int* __restrict__ qhead){
  int i = blockIdx.x*256 + threadIdx.x;
  if (i < 256*128) w2b[i] = f2bf(w2[i]);
  if (i < 512*512){
    int f = i >> 9, e = i & 511;
    short v = f2bf(w3[i]);
    if (e < 256) w3ab[f*256 + e] = v; else w3bb[f*256 + (e-256)] = v;
  }
  if (i < 384*512) w4b[i] = f2bf(w4[i]);
  if (i < 128){ float s = g1[i]*rsqrtf(va1[i] + BN_EPS_C); sc1[i]=s; sh1[i]=be1[i]-mu1[i]*s; }
  if (i < 512){ float s = g2[i]*rsqrtf(va2[i] + BN_EPS_C); sc2[i]=s; sh2[i]=be2[i]-mu2[i]*s; }
  if (i < PB) prog[i] = 0;
  if (i == PB) qhead[0] = 0;
}

// ---------------- launcher ----------------
extern "C" void kernel_launch(void* const* d_in, const int* in_sizes, int n_in,
                              void* d_out, int out_size, void* d_ws, size_t ws_size,
                              hipStream_t stream){
  const float* points = (const float*)d_in[0];
  const float* w1  = (const float*)d_in[1];
  const float* g1  = (const float*)d_in[2];
  const float* be1 = (const float*)d_in[3];
  const float* mu1 = (const float*)d_in[4];
  const float* va1 = (const float*)d_in[5];
  const float* w2  = (const float*)d_in[6];
  const float* b2  = (const float*)d_in[7];
  const float* w3  = (const float*)d_in[8];
  const float* g2  = (const float*)d_in[9];
  const float* be2 = (const float*)d_in[10];
  const float* mu2 = (const float*)d_in[11];
  const float* va2 = (const float*)d_in[12];
  const float* w4  = (const float*)d_in[13];
  const float* b4  = (const float*)d_in[14];
  float* tokens  = (float*)d_out;                       // [PM, 384]
  float* centers = (float*)d_out + (size_t)PM*PTOK;     // [PM, 3]

  // ---- workspace (~4.2 MB total) ----
  char* ws = (char*)d_ws;
  float* grp  = (float*)(ws + 0);              // 262144x3 fp32 = 3 MB
  short* w2b  = (short*)(ws + 3145728ull);     // 256x128 bf16
  short* w3ab = (short*)(ws + 3211264ull);     // 512x256 bf16
  short* w3bb = (short*)(ws + 3473408ull);     // 512x256 bf16
  short* w4b  = (short*)(ws + 3735552ull);     // 384x512 bf16
  float* sc1  = (float*)(ws + 4128768ull);
  float* sh1  = (float*)(ws + 4129280ull);
  float* sc2  = (float*)(ws + 4129792ull);
  float* sh2  = (float*)(ws + 4131840ull);
  int*   prog = (int*)(ws + 4133888ull);       // [16]
  int*   qhead= (int*)(ws + 4133952ull);       // [1]

  prep_kernel<<<1024, 256, 0, stream>>>(w2, w3, w4, g1, be1, mu1, va1, g2, be2, mu2, va2,
                                        w2b, w3ab, w3bb, w4b, sc1, sh1, sc2, sh2,
                                        prog, qhead);
  mega2_kernel<<<PB + NWORK, 1024, 0, stream>>>(points, centers, prog, qhead, grp);
  mlp_kernel<<<PMK/128, 512, 0, stream>>>(grp, w1, sc1, sh1, w2b, b2,
                                          w3ab, w3bb, sc2, sh2, w4b, b4, tokens);
}

// Round 17
// 1044.857 us; speedup vs baseline: 1.5473x; 1.5473x over previous
//
#include <hip/hip_runtime.h>
#include <stdint.h>

// ---------------- problem constants ----------------
#define PB 16            // batches
#define PN 8192          // points per batch
#define PG 512           // FPS samples (centers) per batch
#define PK 32            // knn group size
#define PTOK 384
#define PM (PB*PG)       // 8192 groups total
#define PMK (PM*PK)      // 262144 MLP rows
#define NWORK 240        // knn worker blocks (16 fps + 240 = 256 = #CUs, co-resident)
#define NTASK (PM/4)     // 2048 quad tasks (4 consecutive centers of one batch)
static constexpr float BN_EPS_C = 1e-5f;

typedef short bh8  __attribute__((ext_vector_type(8)));
typedef float f32x4 __attribute__((ext_vector_type(4)));

__device__ __forceinline__ short f2bf(float f){
  unsigned u = __float_as_uint(f);
  unsigned r = u + 0x7fffu + ((u>>16)&1u);   // RNE
  return (short)(r>>16);
}
__device__ __forceinline__ float bf2f(short s){
  return __uint_as_float(((unsigned)(unsigned short)s)<<16);
}
__device__ __forceinline__ void gload16(const void* g, void* l){
  __builtin_amdgcn_global_load_lds((const __attribute__((address_space(1))) unsigned int*)g,
                                   (__attribute__((address_space(3))) unsigned int*)l,
                                   16, 0, 0);
}

// ---------------- 1. mega2: 16 FPS producers + 240 KNN workers (no MFMA) --------
// R15-best configuration. Worker knockout uses a STATIC-indexed select so
// key[32] stays in VGPRs (dynamic key[wj>>8] forced scratch spill).
__global__ __launch_bounds__(1024, 4) void mega2_kernel(
    const float* __restrict__ points, float* __restrict__ centers,
    int* __restrict__ prog, int* __restrict__ qhead,
    float* __restrict__ grp){
#pragma clang fp contract(off)
  __shared__ __align__(16) char SMEM[150528];
  const int t = threadIdx.x;
  const int lane = t & 63;

  if (blockIdx.x < PB){
    // ================= FPS role (proven 504us shape) =================
    const int b = blockIdx.x;
    const float* P = points + (size_t)b*PN*3;
    float4* Lc = (float4*)SMEM;                          // 128 KB
    unsigned short* sidx = (unsigned short*)(SMEM + 131072);  // 16 KB
    int* shist = (int*)(SMEM + 147456);                  // 2 KB
    int* spart = (int*)(SMEM + 149504);                  // 256 B
    unsigned long long* swa = (unsigned long long*)(SMEM + 149760);
    if (t < 512) shist[t] = 0;
    if (t < 3)   swa[t] = 0ull;
    __syncthreads();
    int mycell[8];
#pragma unroll
    for (int i=0;i<8;i++){
      int j = i*1024 + t;
      float x=P[j*3+0], y=P[j*3+1], z=P[j*3+2];
      Lc[j] = make_float4(x,y,z,0.f);
      int qx=(int)fminf(fmaxf((x+4.f)*1.0f,0.f),7.f);
      int qy=(int)fminf(fmaxf((y+4.f)*1.0f,0.f),7.f);
      int qz=(int)fminf(fmaxf((z+4.f)*1.0f,0.f),7.f);
      int mc = (qx&1)|((qx&2)<<2)|((qx&4)<<4)
             | ((qy&1)<<1)|((qy&2)<<3)|((qy&4)<<5)
             | ((qz&1)<<2)|((qz&2)<<4)|((qz&4)<<6);
      mycell[i]=mc;
      atomicAdd(&shist[mc],1);
    }
    __syncthreads();
    if (t < 64){
      int acc=0;
#pragma unroll
      for (int k=0;k<8;k++){ int h=shist[t*8+k]; shist[t*8+k]=acc; acc+=h; }
      spart[t]=acc;
    }
    __syncthreads();
    if (t==0){ int acc=0; for (int k=0;k<64;k++){ int h=spart[k]; spart[k]=acc; acc+=h; } }
    __syncthreads();
    if (t < 64){
      int off=spart[t];
#pragma unroll
      for (int k=0;k<8;k++) shist[t*8+k] += off;
    }
    __syncthreads();
#pragma unroll
    for (int i=0;i<8;i++){
      int j = i*1024 + t;
      int r = atomicAdd(&shist[mycell[i]],1);
      sidx[r] = (unsigned short)j;
    }
    __syncthreads();
    float px[8],py[8],pz[8],md[8]; int lowc[8];
    float tlx=1e30f,tly=1e30f,tlz=1e30f,thx=-1e30f,thy=-1e30f,thz=-1e30f;
#pragma unroll
    for (int i=0;i<8;i++){
      int oj = sidx[t*8+i];
      float4 p4 = Lc[oj];
      float x=p4.x, y=p4.y, z=p4.z;
      px[i]=x; py[i]=y; pz[i]=z; md[i]=1e10f; lowc[i]=PN-1-oj;
      tlx=fminf(tlx,x); thx=fmaxf(thx,x);
      tly=fminf(tly,y); thy=fmaxf(thy,y);
      tlz=fminf(tlz,z); thz=fmaxf(thz,z);
    }
#pragma unroll
    for (int off=32; off; off>>=1){
      tlx=fminf(tlx,__shfl_xor(tlx,off)); thx=fmaxf(thx,__shfl_xor(thx,off));
      tly=fminf(tly,__shfl_xor(tly,off)); thy=fmaxf(thy,__shfl_xor(thy,off));
      tlz=fminf(tlz,__shfl_xor(tlz,off)); thz=fmaxf(thz,__shfl_xor(thz,off));
    }
    unsigned long long wkey = ((unsigned long long)0x7F800000u)<<32;
    float cx=P[0], cy=P[1], cz=P[2];
    if (t==0){ float* c = centers + (size_t)b*PG*3; c[0]=cx; c[1]=cy; c[2]=cz; }
    __syncthreads();
    for (int g=1; g<PG; g++){
      const int sl = g%3, ns = (g+1)%3;
      float ddx=fmaxf(fmaxf(tlx-cx, cx-thx),0.f);
      float ddy=fmaxf(fmaxf(tly-cy, cy-thy),0.f);
      float ddz=fmaxf(fmaxf(tlz-cz, cz-thz),0.f);
      float dmin2=((ddx*ddx+ddy*ddy)+ddz*ddz)*0.999999f;
      if (!(dmin2 >= __uint_as_float((unsigned)(wkey>>32)))){
        unsigned long long bk = 0ull;
#pragma unroll
        for (int i=0;i<8;i++){
          float dx=px[i]-cx, dy=py[i]-cy, dz=pz[i]-cz;
          float d2 = (dx*dx + dy*dy) + dz*dz;
          md[i] = fminf(md[i], d2);
          unsigned long long ki = ((unsigned long long)__float_as_uint(md[i])<<32)
                                | (unsigned)lowc[i];
          if (ki > bk) bk = ki;
        }
#pragma unroll
        for (int mask=32; mask; mask>>=1){
          unsigned long long o = __shfl_xor(bk, mask);
          if (o > bk) bk = o;
        }
        wkey = bk;
      }
      if (lane==0) atomicMax(&swa[sl], wkey);
      if (t==0) swa[ns] = 0ull;
      __syncthreads();
      unsigned long long w = swa[sl];
      int j = PN-1 - (int)(w & 0xFFFFFFFFu);
      float4 c4 = Lc[j];
      cx = c4.x; cy = c4.y; cz = c4.z;
      if (t==0){
        float* cc = centers + ((size_t)b*PG + g)*3;
        cc[0]=cx; cc[1]=cy; cc[2]=cz;
        if ((g & 3) == 3)    // publish quad: centers 0..g now agent-visible
          __hip_atomic_store(prog + b, g + 1, __ATOMIC_RELEASE, __HIP_MEMORY_SCOPE_AGENT);
      }
    }
    // fall through: help drain remaining knn tasks
  }

  // ================= KNN worker role (u32 keys, static knockout) =================
  unsigned long long* ks_k = (unsigned long long*)(SMEM + 149504); // [4][2][4]
  int*   ks_idx = (int*)(SMEM + 149760);           // [4][32]
  float* ks_c   = (float*)(SMEM + 150272);         // [4][3]
  int*   s_task = (int*)(SMEM + 150320);

  for(;;){
    if (t == 0){
      int id = atomicAdd(qhead, 1);
      s_task[0] = id;
      if (id < NTASK){
        int bb = id & (PB-1), qq = id >> 4;
        int need = qq*4 + 4;
        while (__hip_atomic_load(prog + bb, __ATOMIC_ACQUIRE, __HIP_MEMORY_SCOPE_AGENT) < need)
          __builtin_amdgcn_s_sleep(10);
      }
    }
    __syncthreads();
    const int id = s_task[0];
    if (id >= NTASK) break;                        // uniform
    const int b = id & (PB-1), q = id >> 4;
    const int m0 = b*PG + q*4;                     // first center of quad
    const float* P = points + (size_t)b*PN*3;
    const int sub = t >> 8, tt = t & 255;          // 4 subgroups x 256 threads

    if (tt == 0){
      const float* cp = centers + (size_t)(m0 + sub)*3;
      ks_c[sub*3+0] = __hip_atomic_load(cp+0, __ATOMIC_ACQUIRE, __HIP_MEMORY_SCOPE_AGENT);
      ks_c[sub*3+1] = __hip_atomic_load(cp+1, __ATOMIC_ACQUIRE, __HIP_MEMORY_SCOPE_AGENT);
      ks_c[sub*3+2] = __hip_atomic_load(cp+2, __ATOMIC_ACQUIRE, __HIP_MEMORY_SCOPE_AGENT);
    }
    __syncthreads();
    {
      const float cx=ks_c[sub*3+0], cy=ks_c[sub*3+1], cz=ks_c[sub*3+2];
      const float cn = (cx*cx + cy*cy) + cz*cz;
      unsigned key[PK];                            // 32 VGPRs; index implicit in slot
#pragma unroll
      for (int i=0;i<PK;i++){
        int j = i*256 + tt;
        float x=P[j*3+0], y=P[j*3+1], z=P[j*3+2];
        float pn = (x*x + y*y) + z*z;
        float e  = (cx*x + cy*y) + cz*z;
        float d2 = (cn + pn) - 2.0f*e;             // reference formula
        unsigned u = __float_as_uint(d2);
        u ^= (u & 0x80000000u) ? 0xFFFFFFFFu : 0x80000000u;   // total order
        key[i] = u;
      }
      unsigned lmin = key[0]; int li = 0;          // strict <: smallest slot wins
#pragma unroll
      for (int i=1;i<PK;i++) if (key[i] < lmin){ lmin = key[i]; li = i; }
      unsigned long long lkey = ((unsigned long long)lmin << 32)
                              | (unsigned)(li*256 + tt);
      const int widx = tt >> 6;
      for (int it=0; it<PK; it++){
        unsigned long long v = lkey;
#pragma unroll
        for (int off=32; off; off>>=1){
          unsigned long long o = __shfl_down(v, off);
          if (o < v) v = o;
        }
        if (lane==0) ks_k[sub*8 + (it&1)*4 + widx] = v;
        __syncthreads();                           // block-wide, uniform rounds
        unsigned long long w = ks_k[sub*8 + (it&1)*4 + 0];
#pragma unroll
        for (int qq=1;qq<4;qq++){
          unsigned long long o = ks_k[sub*8 + (it&1)*4 + qq];
          if (o < w) w = o;
        }
        int wj = (int)(w & 0xFFFFFFFFull);
        if (tt==0) ks_idx[sub*32 + it] = wj;
        if ((wj & 255) == tt){                     // owner: kill slot (STATIC idx), rescan
          int slot = wj >> 8;
#pragma unroll
          for (int i=0;i<PK;i++) if (i == slot) key[i] = 0xFFFFFFFFu;
          lmin = key[0]; li = 0;
#pragma unroll
          for (int i=1;i<PK;i++) if (key[i] < lmin){ lmin = key[i]; li = i; }
          lkey = ((unsigned long long)lmin << 32) | (unsigned)(li*256 + tt);
        }
      }
      __syncthreads();
      if (tt < PK*3){
        int k = tt/3, c = tt - k*3;
        int j = ks_idx[sub*32 + k];
        grp[((size_t)(m0 + sub)*PK + k)*3 + c] = P[j*3+c] - ks_c[sub*3+c];
      }
    }
    // claim-barrier at loop top separates ks_c/ks_idx reuse across tasks
  }
}

// ---------------- 2. fused MLP (R10-proven, 128-row): layer1->f2->g->f3->f4->pool ----
__global__ __launch_bounds__(512, 2) void mlp_kernel(const float* __restrict__ grp,
                                                     const float* __restrict__ w1,
                                                     const float* __restrict__ sc1,
                                                     const float* __restrict__ sh1,
                                                     const short* __restrict__ w2b,
                                                     const float* __restrict__ b2,
                                                     const short* __restrict__ w3ab,
                                                     const short* __restrict__ w3bb,
                                                     const float* __restrict__ sc2,
                                                     const float* __restrict__ sh2,
                                                     const short* __restrict__ w4b,
                                                     const float* __restrict__ b4,
                                                     float* __restrict__ tokens){
  __shared__ __align__(16) short s_f1f3[16384];    // 32 KB: f1 [4][128][32] then f3-chunk
  __shared__ __align__(16) short s_f2[32768];      // 64 KB: f2 [8][128][32]
  __shared__ __align__(16) short s_g[1024];        //  2 KB: g  [4][256]
  __shared__ __align__(16) short s_bst[24576];     // 48 KB: B staging [2][R][32]
  const int t = threadIdx.x;
  const int lane = t & 63, wid = t >> 6;
  const int mh = wid >> 1, nq = wid & 1;           // 4 M-waves x 2 N-waves
  const int B0 = blockIdx.x * 128;                 // first row of block
  const int G0 = blockIdx.x * 4;                   // first group of block
  const int srow = lane >> 2;                      // staging row within 16-row chunk
  const int scol = (lane & 3) * 8;                 // staging col offset
  const int frow = lane & 15;                      // fragment row
  const int fk   = (lane >> 4) * 8;                // fragment k offset
  const int rb   = (lane >> 4) * 4;                // C/D row base
  const int cb   = lane & 15;                      // C/D col

  // ---- phase A: layer1 into f1 (LDS) ----
  {
    int r = t & 127, dg = t >> 7;                  // thread: row r, d-range dg*32..+31
    float x0 = grp[(size_t)(B0+r)*3 + 0];
    float x1 = grp[(size_t)(B0+r)*3 + 1];
    float x2 = grp[(size_t)(B0+r)*3 + 2];
#pragma unroll
    for (int dd=0; dd<32; dd++){
      int d = dg*32 + dd;
      float a = x0*w1[d*3+0] + x1*w1[d*3+1] + x2*w1[d*3+2];
      float y = a*sc1[d] + sh1[d];
      s_f1f3[dg*4096 + r*32 + dd] = f2bf(fmaxf(y, 0.f));
    }
  }
  __syncthreads();

  // ---- phase B: f2 = f1 @ w2^T + b2 (K=128, N=256) ----
  {
    f32x4 accB[2][8] = {};
    for (int k0=0; k0<128; k0+=64){
      for (int cc=wid; cc<32; cc+=8){              // stage w2 [2][256][32]
        int sub = cc & 1, rc = cc >> 1;
        int r = rc*16 + srow;
        gload16(w2b + (size_t)r*128 + k0 + sub*32 + scol, &s_bst[sub*8192 + rc*512]);
      }
      __syncthreads();
#pragma unroll
      for (int sub=0; sub<2; sub++){
        int kc = (k0 + sub*32) >> 5;
        bh8 af[2], bf[8];
#pragma unroll
        for (int i=0;i<2;i++)
          af[i] = *(const bh8*)&s_f1f3[kc*4096 + (mh*32 + i*16 + frow)*32 + fk];
#pragma unroll
        for (int j=0;j<8;j++)
          bf[j] = *(const bh8*)&s_bst[sub*8192 + (nq*128 + j*16 + frow)*32 + fk];
#pragma unroll
        for (int i=0;i<2;i++)
#pragma unroll
          for (int j=0;j<8;j++)
            accB[i][j] = __builtin_amdgcn_mfma_f32_16x16x32_bf16(af[i], bf[j], accB[i][j], 0,0,0);
      }
      __syncthreads();
    }
    // epilogue: +b2, bf16, write f2 chunks
#pragma unroll
    for (int i=0;i<2;i++)
#pragma unroll
      for (int j=0;j<8;j++){
        int col = nq*128 + j*16 + cb;
#pragma unroll
        for (int r=0;r<4;r++){
          int row = mh*32 + i*16 + rb + r;
          s_f2[(col>>5)*4096 + row*32 + (col&31)] = f2bf(accB[i][j][r] + b2[col]);
        }
      }
  }
  __syncthreads();

  // ---- phase C: g = maxpool_k(f2) per group ----
  {
#pragma unroll
    for (int task=0; task<2; task++){
      int g = (t>>8) + task*2;                     // 0..3
      int col = t & 255;
      int kc = col >> 5, c5 = col & 31;
      float mx = -3.4e38f;
#pragma unroll
      for (int kk=0; kk<PK; kk++)
        mx = fmaxf(mx, bf2f(s_f2[kc*4096 + (g*32 + kk)*32 + c5]));
      s_g[g*256 + col] = f2bf(mx);
    }
  }
  __syncthreads();

  // ---- phases D+E: f3 chunks (concat GEMM) + f4 partial accumulation ----
  f32x4 acc4[2][12] = {};                          // persistent: 128 x 384 over 8 waves
  for (int nc=0; nc<4; nc++){
    // --- D: f3c[128][128] = relu(bn2([g,f2] @ w3[nc*128..][:]^T)) ---
    f32x4 acc3[2][4] = {};
    for (int k0=0; k0<512; k0+=64){
      const short* w3s = (k0 < 256) ? w3ab : w3bb;
      int kk0 = (k0 < 256) ? k0 : (k0 - 256);
      for (int cc=wid; cc<16; cc+=8){              // stage w3 [2][128][32]
        int sub = cc & 1, rc = cc >> 1;
        int r = nc*128 + rc*16 + srow;
        gload16(w3s + (size_t)r*256 + kk0 + sub*32 + scol, &s_bst[sub*4096 + rc*512]);
      }
      __syncthreads();
#pragma unroll
      for (int sub=0; sub<2; sub++){
        int k = k0 + sub*32;                       // concat-k
        bh8 af[2], bf[4];
        if (k < 256){
#pragma unroll
          for (int i=0;i<2;i++)                    // whole wave-tile = one group: broadcast
            af[i] = *(const bh8*)&s_g[mh*256 + k + fk];
        } else {
          int kc = (k - 256) >> 5;
#pragma unroll
          for (int i=0;i<2;i++)
            af[i] = *(const bh8*)&s_f2[kc*4096 + (mh*32 + i*16 + frow)*32 + fk];
        }
#pragma unroll
        for (int j=0;j<4;j++)
          bf[j] = *(const bh8*)&s_bst[sub*4096 + (nq*64 + j*16 + frow)*32 + fk];
#pragma unroll
        for (int i=0;i<2;i++)
#pragma unroll
          for (int j=0;j<4;j++)
            acc3[i][j] = __builtin_amdgcn_mfma_f32_16x16x32_bf16(af[i], bf[j], acc3[i][j], 0,0,0);
      }
      __syncthreads();
    }
    // D epilogue: bn2 + relu + bf16 -> f3 chunk (reuses f1 region)
#pragma unroll
    for (int i=0;i<2;i++)
#pragma unroll
      for (int j=0;j<4;j++){
        int cl = nq*64 + j*16 + cb;                // local f-col 0..127
        int f  = nc*128 + cl;
        float s = sc2[f], h = sh2[f];
#pragma unroll
        for (int r=0;r<4;r++){
          int row = mh*32 + i*16 + rb + r;
          float v = acc3[i][j][r]*s + h;
          s_f1f3[(cl>>5)*4096 + row*32 + (cl&31)] = f2bf(fmaxf(v, 0.f));
        }
      }
    __syncthreads();
    // --- E: acc4 += f3c @ w4[:, nc*128..]^T (K-chunk of 128) ---
    for (int kk0=0; kk0<128; kk0+=64){
      for (int cc=wid; cc<48; cc+=8){              // stage w4 [2][384][32]
        int sub = cc & 1, rc = cc >> 1;
        int r = rc*16 + srow;
        gload16(w4b + (size_t)r*512 + nc*128 + kk0 + sub*32 + scol, &s_bst[sub*12288 + rc*512]);
      }
      __syncthreads();
#pragma unroll
      for (int sub=0; sub<2; sub++){
        int kc = (kk0 + sub*32) >> 5;
        bh8 af[2], bf[12];
#pragma unroll
        for (int i=0;i<2;i++)
          af[i] = *(const bh8*)&s_f1f3[kc*4096 + (mh*32 + i*16 + frow)*32 + fk];
#pragma unroll
        for (int j=0;j<12;j++)
          bf[j] = *(const bh8*)&s_bst[sub*12288 + (nq*192 + j*16 + frow)*32 + fk];
#pragma unroll
        for (int i=0;i<2;i++)
#pragma unroll
          for (int j=0;j<12;j++)
            acc4[i][j] = __builtin_amdgcn_mfma_f32_16x16x32_bf16(af[i], bf[j], acc4[i][j], 0,0,0);
      }
      __syncthreads();
    }
  }

  // ---- phase F: tokens = maxpool_k(f4) + b4 (wave mh owns group mh) ----
#pragma unroll
  for (int j=0;j<12;j++){
    int col = nq*192 + j*16 + cb;
    float mx = -3.4e38f;
#pragma unroll
    for (int i=0;i<2;i++)
#pragma unroll
      for (int r=0;r<4;r++)
        mx = fmaxf(mx, acc4[i][j][r]);
    mx = fmaxf(mx, __shfl_xor(mx, 16));
    mx = fmaxf(mx, __shfl_xor(mx, 32));
    if (lane < 16)
      tokens[(size_t)(G0 + mh)*PTOK + col] = mx + b4[col];
  }
}

// ---------------- 0. weight conversion + BN folding + sync reset ----------------
__global__ __launch_bounds__(256) void prep_kernel(const float* __restrict__ w2,
    const float* __restrict__ w3, const float* __restrict__ w4,
    const float* __restrict__ g1, const float* __restrict__ be1,
    const float* __restrict__ mu1, const float* __restrict__ va1,
    const float* __restrict__ g2, const float* __restrict__ be2,
    const float* __restrict__ mu2, const float* __restrict__ va2,
    short* __restrict__ w2b, short* __restrict__ w3ab, short* __restrict__ w3bb,
    short* __restrict__ w4b, float* __restrict__ sc1, float* __restrict__ sh1,
    float* __restrict__ sc2, float* __restrict__ sh2,
    int* __restrict__ prog, int* __restrict__ qhead){
  int i = blockIdx.x*256 + threadIdx.x;
  if (i < 256*128) w2b[i] = f2bf(w2[i]);
  if (i < 512*512){
    int f = i >> 9, e = i & 511;
    short v = f2bf(w3[i]);
    if (e < 256) w3ab[f*256 + e] = v; else w3bb[f*256 + (e-256)] = v;
  }
  if (i < 384*512) w4b[i] = f2bf(w4[i]);
  if (i < 128){ float s = g1[i]*rsqrtf(va1[i] + BN_EPS_C); sc1[i]=s; sh1[i]=be1[i]-mu1[i]*s; }
  if (i < 512){ float s = g2[i]*rsqrtf(va2[i] + BN_EPS_C); sc2[i]=s; sh2[i]=be2[i]-mu2[i]*s; }
  if (i < PB) prog[i] = 0;
  if (i == PB) qhead[0] = 0;
}

// ---------------- launcher ----------------
extern "C" void kernel_launch(void* const* d_in, const int* in_sizes, int n_in,
                              void* d_out, int out_size, void* d_ws, size_t ws_size,
                              hipStream_t stream){
  const float* points = (const float*)d_in[0];
  const float* w1  = (const float*)d_in[1];
  const float* g1  = (const float*)d_in[2];
  const float* be1 = (const float*)d_in[3];
  const float* mu1 = (const float*)d_in[4];
  const float* va1 = (const float*)d_in[5];
  const float* w2  = (const float*)d_in[6];
  const float* b2  = (const float*)d_in[7];
  const float* w3  = (const float*)d_in[8];
  const float* g2  = (const float*)d_in[9];
  const float* be2 = (const float*)d_in[10];
  const float* mu2 = (const float*)d_in[11];
  const float* va2 = (const float*)d_in[12];
  const float* w4  = (const float*)d_in[13];
  const float* b4  = (const float*)d_in[14];
  float* tokens  = (float*)d_out;                       // [PM, 384]
  float* centers = (float*)d_out + (size_t)PM*PTOK;     // [PM, 3]

  // ---- workspace (~4.2 MB total) ----
  char* ws = (char*)d_ws;
  float* grp  = (float*)(ws + 0);              // 262144x3 fp32 = 3 MB
  short* w2b  = (short*)(ws + 3145728ull);     // 256x128 bf16
  short* w3ab = (short*)(ws + 3211264ull);     // 512x256 bf16
  short* w3bb = (short*)(ws + 3473408ull);     // 512x256 bf16
  short* w4b  = (short*)(ws + 3735552ull);     // 384x512 bf16
  float* sc1  = (float*)(ws + 4128768ull);
  float* sh1  = (float*)(ws + 4129280ull);
  float* sc2  = (float*)(ws + 4129792ull);
  float* sh2  = (float*)(ws + 4131840ull);
  int*   prog = (int*)(ws + 4133888ull);       // [16]
  int*   qhead= (int*)(ws + 4133952ull);       // [1]

  prep_kernel<<<1024, 256, 0, stream>>>(w2, w3, w4, g1, be1, mu1, va1, g2, be2, mu2, va2,
                                        w2b, w3ab, w3bb, w4b, sc1, sh1, sc2, sh2,
                                        prog, qhead);
  mega2_kernel<<<PB + NWORK, 1024, 0, stream>>>(points, centers, prog, qhead, grp);
  mlp_kernel<<<PMK/128, 512, 0, stream>>>(grp, w1, sc1, sh1, w2b, b2,
                                          w3ab, w3bb, sc2, sh2, w4b, b4, tokens);
}

// Round 18
// 1025.083 us; speedup vs baseline: 1.5772x; 1.0193x over previous
//
#include <hip/hip_runtime.h>
#include <stdint.h>

// ---------------- problem constants ----------------
#define PB 16            // batches
#define PN 8192          // points per batch
#define PG 512           // FPS samples (centers) per batch
#define PK 32            // knn group size
#define PTOK 384
#define PM (PB*PG)       // 8192 groups total
#define PMK (PM*PK)      // 262144 MLP rows
#define NWORK 240        // knn worker blocks (16 fps + 240 = 256 = #CUs, co-resident)
#define NTASK (PM/4)     // 2048 quad tasks (4 consecutive centers of one batch)
static constexpr float BN_EPS_C = 1e-5f;

typedef short bh8  __attribute__((ext_vector_type(8)));
typedef float f32x4 __attribute__((ext_vector_type(4)));

__device__ __forceinline__ short f2bf(float f){
  unsigned u = __float_as_uint(f);
  unsigned r = u + 0x7fffu + ((u>>16)&1u);   // RNE
  return (short)(r>>16);
}
__device__ __forceinline__ float bf2f(short s){
  return __uint_as_float(((unsigned)(unsigned short)s)<<16);
}
__device__ __forceinline__ void gload16(const void* g, void* l){
  __builtin_amdgcn_global_load_lds((const __attribute__((address_space(1))) unsigned int*)g,
                                   (__attribute__((address_space(3))) unsigned int*)l,
                                   16, 0, 0);
}

// ---------------- 1. mega2: 16 FPS producers + 240 KNN workers (no MFMA) --------
// R18 worker fix: per-thread knn keys live in LDS (s_key[i*1024+t], lane-stride
// 4B conflict-free; aliases the fps Lc region which is dead in worker role).
// R11-R17 kept key[32] in "registers" but the 64-VGPR union allocation spilled
// them to scratch: 42 MB of WRITE traffic concurrent with fps (74 us/task).
// LDS keys drop per-thread state to ~25 regs -> no spill. Math identical (R7-proven).
__global__ __launch_bounds__(1024, 4) void mega2_kernel(
    const float* __restrict__ points, float* __restrict__ centers,
    int* __restrict__ prog, int* __restrict__ qhead,
    float* __restrict__ grp){
#pragma clang fp contract(off)
  __shared__ __align__(16) char SMEM[150528];
  const int t = threadIdx.x;
  const int lane = t & 63;

  if (blockIdx.x < PB){
    // ================= FPS role (proven 504us shape) =================
    const int b = blockIdx.x;
    const float* P = points + (size_t)b*PN*3;
    float4* Lc = (float4*)SMEM;                          // 128 KB
    unsigned short* sidx = (unsigned short*)(SMEM + 131072);  // 16 KB
    int* shist = (int*)(SMEM + 147456);                  // 2 KB
    int* spart = (int*)(SMEM + 149504);                  // 256 B
    unsigned long long* swa = (unsigned long long*)(SMEM + 149760);
    if (t < 512) shist[t] = 0;
    if (t < 3)   swa[t] = 0ull;
    __syncthreads();
    int mycell[8];
#pragma unroll
    for (int i=0;i<8;i++){
      int j = i*1024 + t;
      float x=P[j*3+0], y=P[j*3+1], z=P[j*3+2];
      Lc[j] = make_float4(x,y,z,0.f);
      int qx=(int)fminf(fmaxf((x+4.f)*1.0f,0.f),7.f);
      int qy=(int)fminf(fmaxf((y+4.f)*1.0f,0.f),7.f);
      int qz=(int)fminf(fmaxf((z+4.f)*1.0f,0.f),7.f);
      int mc = (qx&1)|((qx&2)<<2)|((qx&4)<<4)
             | ((qy&1)<<1)|((qy&2)<<3)|((qy&4)<<5)
             | ((qz&1)<<2)|((qz&2)<<4)|((qz&4)<<6);
      mycell[i]=mc;
      atomicAdd(&shist[mc],1);
    }
    __syncthreads();
    if (t < 64){
      int acc=0;
#pragma unroll
      for (int k=0;k<8;k++){ int h=shist[t*8+k]; shist[t*8+k]=acc; acc+=h; }
      spart[t]=acc;
    }
    __syncthreads();
    if (t==0){ int acc=0; for (int k=0;k<64;k++){ int h=spart[k]; spart[k]=acc; acc+=h; } }
    __syncthreads();
    if (t < 64){
      int off=spart[t];
#pragma unroll
      for (int k=0;k<8;k++) shist[t*8+k] += off;
    }
    __syncthreads();
#pragma unroll
    for (int i=0;i<8;i++){
      int j = i*1024 + t;
      int r = atomicAdd(&shist[mycell[i]],1);
      sidx[r] = (unsigned short)j;
    }
    __syncthreads();
    float px[8],py[8],pz[8],md[8]; int lowc[8];
    float tlx=1e30f,tly=1e30f,tlz=1e30f,thx=-1e30f,thy=-1e30f,thz=-1e30f;
#pragma unroll
    for (int i=0;i<8;i++){
      int oj = sidx[t*8+i];
      float4 p4 = Lc[oj];
      float x=p4.x, y=p4.y, z=p4.z;
      px[i]=x; py[i]=y; pz[i]=z; md[i]=1e10f; lowc[i]=PN-1-oj;
      tlx=fminf(tlx,x); thx=fmaxf(thx,x);
      tly=fminf(tly,y); thy=fmaxf(thy,y);
      tlz=fminf(tlz,z); thz=fmaxf(thz,z);
    }
#pragma unroll
    for (int off=32; off; off>>=1){
      tlx=fminf(tlx,__shfl_xor(tlx,off)); thx=fmaxf(thx,__shfl_xor(thx,off));
      tly=fminf(tly,__shfl_xor(tly,off)); thy=fmaxf(thy,__shfl_xor(thy,off));
      tlz=fminf(tlz,__shfl_xor(tlz,off)); thz=fmaxf(thz,__shfl_xor(thz,off));
    }
    unsigned long long wkey = ((unsigned long long)0x7F800000u)<<32;
    float cx=P[0], cy=P[1], cz=P[2];
    if (t==0){ float* c = centers + (size_t)b*PG*3; c[0]=cx; c[1]=cy; c[2]=cz; }
    __syncthreads();
    for (int g=1; g<PG; g++){
      const int sl = g%3, ns = (g+1)%3;
      float ddx=fmaxf(fmaxf(tlx-cx, cx-thx),0.f);
      float ddy=fmaxf(fmaxf(tly-cy, cy-thy),0.f);
      float ddz=fmaxf(fmaxf(tlz-cz, cz-thz),0.f);
      float dmin2=((ddx*ddx+ddy*ddy)+ddz*ddz)*0.999999f;
      if (!(dmin2 >= __uint_as_float((unsigned)(wkey>>32)))){
        unsigned long long bk = 0ull;
#pragma unroll
        for (int i=0;i<8;i++){
          float dx=px[i]-cx, dy=py[i]-cy, dz=pz[i]-cz;
          float d2 = (dx*dx + dy*dy) + dz*dz;
          md[i] = fminf(md[i], d2);
          unsigned long long ki = ((unsigned long long)__float_as_uint(md[i])<<32)
                                | (unsigned)lowc[i];
          if (ki > bk) bk = ki;
        }
#pragma unroll
        for (int mask=32; mask; mask>>=1){
          unsigned long long o = __shfl_xor(bk, mask);
          if (o > bk) bk = o;
        }
        wkey = bk;
      }
      if (lane==0) atomicMax(&swa[sl], wkey);
      if (t==0) swa[ns] = 0ull;
      __syncthreads();
      unsigned long long w = swa[sl];
      int j = PN-1 - (int)(w & 0xFFFFFFFFu);
      float4 c4 = Lc[j];
      cx = c4.x; cy = c4.y; cz = c4.z;
      if (t==0){
        float* cc = centers + ((size_t)b*PG + g)*3;
        cc[0]=cx; cc[1]=cy; cc[2]=cz;
        if ((g & 3) == 3)    // publish quad: centers 0..g now agent-visible
          __hip_atomic_store(prog + b, g + 1, __ATOMIC_RELEASE, __HIP_MEMORY_SCOPE_AGENT);
      }
    }
    // fall through: help drain remaining knn tasks (Lc now dead -> s_key aliases it)
  }

  // ================= KNN worker role: per-thread keys in LDS =================
  unsigned* s_key = (unsigned*)SMEM;               // [32][1024] u32 = 128 KB
  unsigned long long* ks_k = (unsigned long long*)(SMEM + 149504); // [4][2][4]
  int*   ks_idx = (int*)(SMEM + 149760);           // [4][32]
  float* ks_c   = (float*)(SMEM + 150272);         // [4][3]
  int*   s_task = (int*)(SMEM + 150320);

  for(;;){
    if (t == 0){
      int id = atomicAdd(qhead, 1);
      s_task[0] = id;
      if (id < NTASK){
        int bb = id & (PB-1), qq = id >> 4;
        int need = qq*4 + 4;
        while (__hip_atomic_load(prog + bb, __ATOMIC_ACQUIRE, __HIP_MEMORY_SCOPE_AGENT) < need)
          __builtin_amdgcn_s_sleep(10);
      }
    }
    __syncthreads();
    const int id = s_task[0];
    if (id >= NTASK) break;                        // uniform
    const int b = id & (PB-1), q = id >> 4;
    const int m0 = b*PG + q*4;                     // first center of quad
    const float* P = points + (size_t)b*PN*3;
    const int sub = t >> 8, tt = t & 255;          // 4 subgroups x 256 threads

    if (tt == 0){
      const float* cp = centers + (size_t)(m0 + sub)*3;
      ks_c[sub*3+0] = __hip_atomic_load(cp+0, __ATOMIC_ACQUIRE, __HIP_MEMORY_SCOPE_AGENT);
      ks_c[sub*3+1] = __hip_atomic_load(cp+1, __ATOMIC_ACQUIRE, __HIP_MEMORY_SCOPE_AGENT);
      ks_c[sub*3+2] = __hip_atomic_load(cp+2, __ATOMIC_ACQUIRE, __HIP_MEMORY_SCOPE_AGENT);
    }
    __syncthreads();
    {
      const float cx=ks_c[sub*3+0], cy=ks_c[sub*3+1], cz=ks_c[sub*3+2];
      const float cn = (cx*cx + cy*cy) + cz*cz;
      unsigned lmin = 0xFFFFFFFFu; int li = 0;
#pragma unroll
      for (int i=0;i<PK;i++){
        int j = i*256 + tt;
        float x=P[j*3+0], y=P[j*3+1], z=P[j*3+2];
        float pn = (x*x + y*y) + z*z;
        float e  = (cx*x + cy*y) + cz*z;
        float d2 = (cn + pn) - 2.0f*e;             // reference formula
        unsigned u = __float_as_uint(d2);
        u ^= (u & 0x80000000u) ? 0xFFFFFFFFu : 0x80000000u;   // total order
        s_key[i*1024 + t] = u;                     // lanes stride 4B: conflict-free
        if (u < lmin){ lmin = u; li = i; }         // strict <: smallest slot wins
      }
      unsigned long long lkey = ((unsigned long long)lmin << 32)
                              | (unsigned)(li*256 + tt);
      const int widx = tt >> 6;
      for (int it=0; it<PK; it++){
        unsigned long long v = lkey;
#pragma unroll
        for (int off=32; off; off>>=1){
          unsigned long long o = __shfl_down(v, off);
          if (o < v) v = o;
        }
        if (lane==0) ks_k[sub*8 + (it&1)*4 + widx] = v;
        __syncthreads();                           // block-wide, uniform rounds
        unsigned long long w = ks_k[sub*8 + (it&1)*4 + 0];
#pragma unroll
        for (int qq=1;qq<4;qq++){
          unsigned long long o = ks_k[sub*8 + (it&1)*4 + qq];
          if (o < w) w = o;
        }
        int wj = (int)(w & 0xFFFFFFFFull);
        if (tt==0) ks_idx[sub*32 + it] = wj;
        if ((wj & 255) == tt){                     // owner: kill slot in LDS, rescan LDS
          s_key[(wj >> 8)*1024 + t] = 0xFFFFFFFFu;
          unsigned nm = 0xFFFFFFFFu; int ni = 0;
#pragma unroll
          for (int i=0;i<PK;i++){
            unsigned u = s_key[i*1024 + t];
            if (u < nm){ nm = u; ni = i; }
          }
          lkey = ((unsigned long long)nm << 32) | (unsigned)(ni*256 + tt);
        }
      }
      __syncthreads();
      if (tt < PK*3){
        int k = tt/3, c = tt - k*3;
        int j = ks_idx[sub*32 + k];
        grp[((size_t)(m0 + sub)*PK + k)*3 + c] = P[j*3+c] - ks_c[sub*3+c];
      }
      __syncthreads();                             // s_key reused next task
    }
  }
}

// ---------------- 2. fused MLP (R10-proven, 128-row): layer1->f2->g->f3->f4->pool ----
__global__ __launch_bounds__(512, 2) void mlp_kernel(const float* __restrict__ grp,
                                                     const float* __restrict__ w1,
                                                     const float* __restrict__ sc1,
                                                     const float* __restrict__ sh1,
                                                     const short* __restrict__ w2b,
                                                     const float* __restrict__ b2,
                                                     const short* __restrict__ w3ab,
                                                     const short* __restrict__ w3bb,
                                                     const float* __restrict__ sc2,
                                                     const float* __restrict__ sh2,
                                                     const short* __restrict__ w4b,
                                                     const float* __restrict__ b4,
                                                     float* __restrict__ tokens){
  __shared__ __align__(16) short s_f1f3[16384];    // 32 KB: f1 [4][128][32] then f3-chunk
  __shared__ __align__(16) short s_f2[32768];      // 64 KB: f2 [8][128][32]
  __shared__ __align__(16) short s_g[1024];        //  2 KB: g  [4][256]
  __shared__ __align__(16) short s_bst[24576];     // 48 KB: B staging [2][R][32]
  const int t = threadIdx.x;
  const int lane = t & 63, wid = t >> 6;
  const int mh = wid >> 1, nq = wid & 1;           // 4 M-waves x 2 N-waves
  const int B0 = blockIdx.x * 128;                 // first row of block
  const int G0 = blockIdx.x * 4;                   // first group of block
  const int srow = lane >> 2;                      // staging row within 16-row chunk
  const int scol = (lane & 3) * 8;                 // staging col offset
  const int frow = lane & 15;                      // fragment row
  const int fk   = (lane >> 4) * 8;                // fragment k offset
  const int rb   = (lane >> 4) * 4;                // C/D row base
  const int cb   = lane & 15;                      // C/D col

  // ---- phase A: layer1 into f1 (LDS) ----
  {
    int r = t & 127, dg = t >> 7;                  // thread: row r, d-range dg*32..+31
    float x0 = grp[(size_t)(B0+r)*3 + 0];
    float x1 = grp[(size_t)(B0+r)*3 + 1];
    float x2 = grp[(size_t)(B0+r)*3 + 2];
#pragma unroll
    for (int dd=0; dd<32; dd++){
      int d = dg*32 + dd;
      float a = x0*w1[d*3+0] + x1*w1[d*3+1] + x2*w1[d*3+2];
      float y = a*sc1[d] + sh1[d];
      s_f1f3[dg*4096 + r*32 + dd] = f2bf(fmaxf(y, 0.f));
    }
  }
  __syncthreads();

  // ---- phase B: f2 = f1 @ w2^T + b2 (K=128, N=256) ----
  {
    f32x4 accB[2][8] = {};
    for (int k0=0; k0<128; k0+=64){
      for (int cc=wid; cc<32; cc+=8){              // stage w2 [2][256][32]
        int sub = cc & 1, rc = cc >> 1;
        int r = rc*16 + srow;
        gload16(w2b + (size_t)r*128 + k0 + sub*32 + scol, &s_bst[sub*8192 + rc*512]);
      }
      __syncthreads();
#pragma unroll
      for (int sub=0; sub<2; sub++){
        int kc = (k0 + sub*32) >> 5;
        bh8 af[2], bf[8];
#pragma unroll
        for (int i=0;i<2;i++)
          af[i] = *(const bh8*)&s_f1f3[kc*4096 + (mh*32 + i*16 + frow)*32 + fk];
#pragma unroll
        for (int j=0;j<8;j++)
          bf[j] = *(const bh8*)&s_bst[sub*8192 + (nq*128 + j*16 + frow)*32 + fk];
#pragma unroll
        for (int i=0;i<2;i++)
#pragma unroll
          for (int j=0;j<8;j++)
            accB[i][j] = __builtin_amdgcn_mfma_f32_16x16x32_bf16(af[i], bf[j], accB[i][j], 0,0,0);
      }
      __syncthreads();
    }
    // epilogue: +b2, bf16, write f2 chunks
#pragma unroll
    for (int i=0;i<2;i++)
#pragma unroll
      for (int j=0;j<8;j++){
        int col = nq*128 + j*16 + cb;
#pragma unroll
        for (int r=0;r<4;r++){
          int row = mh*32 + i*16 + rb + r;
          s_f2[(col>>5)*4096 + row*32 + (col&31)] = f2bf(accB[i][j][r] + b2[col]);
        }
      }
  }
  __syncthreads();

  // ---- phase C: g = maxpool_k(f2) per group ----
  {
#pragma unroll
    for (int task=0; task<2; task++){
      int g = (t>>8) + task*2;                     // 0..3
      int col = t & 255;
      int kc = col >> 5, c5 = col & 31;
      float mx = -3.4e38f;
#pragma unroll
      for (int kk=0; kk<PK; kk++)
        mx = fmaxf(mx, bf2f(s_f2[kc*4096 + (g*32 + kk)*32 + c5]));
      s_g[g*256 + col] = f2bf(mx);
    }
  }
  __syncthreads();

  // ---- phases D+E: f3 chunks (concat GEMM) + f4 partial accumulation ----
  f32x4 acc4[2][12] = {};                          // persistent: 128 x 384 over 8 waves
  for (int nc=0; nc<4; nc++){
    // --- D: f3c[128][128] = relu(bn2([g,f2] @ w3[nc*128..][:]^T)) ---
    f32x4 acc3[2][4] = {};
    for (int k0=0; k0<512; k0+=64){
      const short* w3s = (k0 < 256) ? w3ab : w3bb;
      int kk0 = (k0 < 256) ? k0 : (k0 - 256);
      for (int cc=wid; cc<16; cc+=8){              // stage w3 [2][128][32]
        int sub = cc & 1, rc = cc >> 1;
        int r = nc*128 + rc*16 + srow;
        gload16(w3s + (size_t)r*256 + kk0 + sub*32 + scol, &s_bst[sub*4096 + rc*512]);
      }
      __syncthreads();
#pragma unroll
      for (int sub=0; sub<2; sub++){
        int k = k0 + sub*32;                       // concat-k
        bh8 af[2], bf[4];
        if (k < 256){
#pragma unroll
          for (int i=0;i<2;i++)                    // whole wave-tile = one group: broadcast
            af[i] = *(const bh8*)&s_g[mh*256 + k + fk];
        } else {
          int kc = (k - 256) >> 5;
#pragma unroll
          for (int i=0;i<2;i++)
            af[i] = *(const bh8*)&s_f2[kc*4096 + (mh*32 + i*16 + frow)*32 + fk];
        }
#pragma unroll
        for (int j=0;j<4;j++)
          bf[j] = *(const bh8*)&s_bst[sub*4096 + (nq*64 + j*16 + frow)*32 + fk];
#pragma unroll
        for (int i=0;i<2;i++)
#pragma unroll
          for (int j=0;j<4;j++)
            acc3[i][j] = __builtin_amdgcn_mfma_f32_16x16x32_bf16(af[i], bf[j], acc3[i][j], 0,0,0);
      }
      __syncthreads();
    }
    // D epilogue: bn2 + relu + bf16 -> f3 chunk (reuses f1 region)
#pragma unroll
    for (int i=0;i<2;i++)
#pragma unroll
      for (int j=0;j<4;j++){
        int cl = nq*64 + j*16 + cb;                // local f-col 0..127
        int f  = nc*128 + cl;
        float s = sc2[f], h = sh2[f];
#pragma unroll
        for (int r=0;r<4;r++){
          int row = mh*32 + i*16 + rb + r;
          float v = acc3[i][j][r]*s + h;
          s_f1f3[(cl>>5)*4096 + row*32 + (cl&31)] = f2bf(fmaxf(v, 0.f));
        }
      }
    __syncthreads();
    // --- E: acc4 += f3c @ w4[:, nc*128..]^T (K-chunk of 128) ---
    for (int kk0=0; kk0<128; kk0+=64){
      for (int cc=wid; cc<48; cc+=8){              // stage w4 [2][384][32]
        int sub = cc & 1, rc = cc >> 1;
        int r = rc*16 + srow;
        gload16(w4b + (size_t)r*512 + nc*128 + kk0 + sub*32 + scol, &s_bst[sub*12288 + rc*512]);
      }
      __syncthreads();
#pragma unroll
      for (int sub=0; sub<2; sub++){
        int kc = (kk0 + sub*32) >> 5;
        bh8 af[2], bf[12];
#pragma unroll
        for (int i=0;i<2;i++)
          af[i] = *(const bh8*)&s_f1f3[kc*4096 + (mh*32 + i*16 + frow)*32 + fk];
#pragma unroll
        for (int j=0;j<12;j++)
          bf[j] = *(const bh8*)&s_bst[sub*12288 + (nq*192 + j*16 + frow)*32 + fk];
#pragma unroll
        for (int i=0;i<2;i++)
#pragma unroll
          for (int j=0;j<12;j++)
            acc4[i][j] = __builtin_amdgcn_mfma_f32_16x16x32_bf16(af[i], bf[j], acc4[i][j], 0,0,0);
      }
      __syncthreads();
    }
  }

  // ---- phase F: tokens = maxpool_k(f4) + b4 (wave mh owns group mh) ----
#pragma unroll
  for (int j=0;j<12;j++){
    int col = nq*192 + j*16 + cb;
    float mx = -3.4e38f;
#pragma unroll
    for (int i=0;i<2;i++)
#pragma unroll
      for (int r=0;r<4;r++)
        mx = fmaxf(mx, acc4[i][j][r]);
    mx = fmaxf(mx, __shfl_xor(mx, 16));
    mx = fmaxf(mx, __shfl_xor(mx, 32));
    if (lane < 16)
      tokens[(size_t)(G0 + mh)*PTOK + col] = mx + b4[col];
  }
}

// ---------------- 0. weight conversion + BN folding + sync reset ----------------
__global__ __launch_bounds__(256) void prep_kernel(const float* __restrict__ w2,
    const float* __restrict__ w3, const float* __restrict__ w4,
    const float* __restrict__ g1, const float* __restrict__ be1,
    const float* __restrict__ mu1, const float* __restrict__ va1,
    const float* __restrict__ g2, const float* __restrict__ be2,
    const float* __restrict__ mu2, const float* __restrict__ va2,
    short* __restrict__ w2b, short* __restrict__ w3ab, short* __restrict__ w3bb,
    short* __restrict__ w4b, float* __restrict__ sc1, float* __restrict__ sh1,
    float* __restrict__ sc2, float* __restrict__ sh2,
    int* __restrict__ prog, int* __restrict__ qhead){
  int i = blockIdx.x*256 + threadIdx.x;
  if (i < 256*128) w2b[i] = f2bf(w2[i]);
  if (i < 512*512){
    int f = i >> 9, e = i & 511;
    short v = f2bf(w3[i]);
    if (e < 256) w3ab[f*256 + e] = v; else w3bb[f*256 + (e-256)] = v;
  }
  if (i < 384*512) w4b[i] = f2bf(w4[i]);
  if (i < 128){ float s = g1[i]*rsqrtf(va1[i] + BN_EPS_C); sc1[i]=s; sh1[i]=be1[i]-mu1[i]*s; }
  if (i < 512){ float s = g2[i]*rsqrtf(va2[i] + BN_EPS_C); sc2[i]=s; sh2[i]=be2[i]-mu2[i]*s; }
  if (i < PB) prog[i] = 0;
  if (i == PB) qhead[0] = 0;
}

// ---------------- launcher ----------------
extern "C" void kernel_launch(void* const* d_in, const int* in_sizes, int n_in,
                              void* d_out, int out_size, void* d_ws, size_t ws_size,
                              hipStream_t stream){
  const float* points = (const float*)d_in[0];
  const float* w1  = (const float*)d_in[1];
  const float* g1  = (const float*)d_in[2];
  const float* be1 = (const float*)d_in[3];
  const float* mu1 = (const float*)d_in[4];
  const float* va1 = (const float*)d_in[5];
  const float* w2  = (const float*)d_in[6];
  const float* b2  = (const float*)d_in[7];
  const float* w3  = (const float*)d_in[8];
  const float* g2  = (const float*)d_in[9];
  const float* be2 = (const float*)d_in[10];
  const float* mu2 = (const float*)d_in[11];
  const float* va2 = (const float*)d_in[12];
  const float* w4  = (const float*)d_in[13];
  const float* b4  = (const float*)d_in[14];
  float* tokens  = (float*)d_out;                       // [PM, 384]
  float* centers = (float*)d_out + (size_t)PM*PTOK;     // [PM, 3]

  // ---- workspace (~4.2 MB total) ----
  char* ws = (char*)d_ws;
  float* grp  = (float*)(ws + 0);              // 262144x3 fp32 = 3 MB
  short* w2b  = (short*)(ws + 3145728ull);     // 256x128 bf16
  short* w3ab = (short*)(ws + 3211264ull);     // 512x256 bf16
  short* w3bb = (short*)(ws + 3473408ull);     // 512x256 bf16
  short* w4b  = (short*)(ws + 3735552ull);     // 384x512 bf16
  float* sc1  = (float*)(ws + 4128768ull);
  float* sh1  = (float*)(ws + 4129280ull);
  float* sc2  = (float*)(ws + 4129792ull);
  float* sh2  = (float*)(ws + 4131840ull);
  int*   prog = (int*)(ws + 4133888ull);       // [16]
  int*   qhead= (int*)(ws + 4133952ull);       // [1]

  prep_kernel<<<1024, 256, 0, stream>>>(w2, w3, w4, g1, be1, mu1, va1, g2, be2, mu2, va2,
                                        w2b, w3ab, w3bb, w4b, sc1, sh1, sc2, sh2,
                                        prog, qhead);
  mega2_kernel<<<PB + NWORK, 1024, 0, stream>>>(points, centers, prog, qhead, grp);
  mlp_kernel<<<PMK/128, 512, 0, stream>>>(grp, w1, sc1, sh1, w2b, b2,
                                          w3ab, w3bb, sc2, sh2, w4b, b4, tokens);
}